// Round 1
// baseline (364.631 us; speedup 1.0000x reference)
//
#include <hip/hip_runtime.h>

typedef __bf16 bf16_t;
typedef bf16_t bf16x4 __attribute__((ext_vector_type(4)));
typedef bf16_t bf16x8 __attribute__((ext_vector_type(8)));
typedef float f32x4 __attribute__((ext_vector_type(4)));

#define B_ 4
#define T_ 2048
#define C_ 1024
#define H_ 16
#define D_ 64

// global -> LDS direct copy, 16B per lane; LDS dest must be wave-uniform base
// (HW adds lane*16). Source is per-lane (pre-swizzled to realize LDS swizzle).
#define GLDS(g, l)                                                          \
  __builtin_amdgcn_global_load_lds(                                         \
      (const __attribute__((address_space(1))) void*)(g),                   \
      (__attribute__((address_space(3))) void*)(l), 16, 0, 0)

static __device__ __forceinline__ f32x4 mfma16(bf16x8 a, bf16x8 b, f32x4 c) {
  return __builtin_amdgcn_mfma_f32_16x16x32_bf16(a, b, c, 0, 0, 0);
}

// ---------------------------------------------------------------- convert
__global__ void cvt_f32_bf16(const float* __restrict__ in,
                             bf16_t* __restrict__ out, int n4) {
  int i = blockIdx.x * blockDim.x + threadIdx.x;
  if (i < n4) {
    float4 v = ((const float4*)in)[i];
    bf16x4 o = {(bf16_t)v.x, (bf16_t)v.y, (bf16_t)v.z, (bf16_t)v.w};
    ((bf16x4*)out)[i] = o;
  }
}

// ------------------------------------------------------------ GEMM main loop
// C = A(MxK) * W(NxK)^T, 128x128 tile, BK=64, 256 threads = 2x2 waves,
// each wave 64x64 = 4x4 fragments of 16x16x32 bf16 MFMA.
// LDS tiles [128 rows][64 bf16] (128B rows), XOR-swizzled 16B chunks:
// phys_chunk = chunk ^ (row & 7). Staged linearly via global_load_lds with
// inverse-swizzled global source (same involution).
__device__ __forceinline__ void gemm_mainloop(const bf16_t* __restrict__ A,
                                              const bf16_t* __restrict__ W,
                                              bf16_t* lA, bf16_t* lB, int row0,
                                              int col0, f32x4 (&acc)[4][4]) {
  const int tid = threadIdx.x;
  const int wave = tid >> 6, lane = tid & 63;
  const int wr = wave >> 1, wc = wave & 1;
  for (int k0 = 0; k0 < C_; k0 += 64) {
#pragma unroll
    for (int it = 0; it < 4; ++it) {
      const int off = (it * 4 + wave) * 1024;  // bytes, wave-uniform
      const int lin = off + lane * 16;
      const int r = lin >> 7;
      const int c = ((lin >> 4) & 7) ^ (r & 7);
      GLDS(A + (size_t)(row0 + r) * C_ + k0 + c * 8, lA + (off >> 1));
      GLDS(W + (size_t)(col0 + r) * C_ + k0 + c * 8, lB + (off >> 1));
    }
    __syncthreads();
#pragma unroll
    for (int s = 0; s < 2; ++s) {
      bf16x8 af[4], bfr[4];
#pragma unroll
      for (int m = 0; m < 4; ++m) {
        const int r = wr * 64 + m * 16 + (lane & 15);
        const int c = s * 4 + (lane >> 4);
        af[m] = *(const bf16x8*)((const char*)lA + r * 128 +
                                 ((c ^ (r & 7)) << 4));
      }
#pragma unroll
      for (int n = 0; n < 4; ++n) {
        const int r = wc * 64 + n * 16 + (lane & 15);
        const int c = s * 4 + (lane >> 4);
        bfr[n] = *(const bf16x8*)((const char*)lB + r * 128 +
                                  ((c ^ (r & 7)) << 4));
      }
#pragma unroll
      for (int m = 0; m < 4; ++m)
#pragma unroll
        for (int n = 0; n < 4; ++n) acc[m][n] = mfma16(af[m], bfr[n], acc[m][n]);
    }
    __syncthreads();
  }
}

// QKV projection. z=0: Q -> [B][H][T][D]; z=1: K -> [B][H][T][D];
// z=2: V -> transposed [B][H][D][T] so PV's B-operand is natural N x K.
__global__ __launch_bounds__(256) void gemm_qkv(
    const bf16_t* __restrict__ xb, const bf16_t* __restrict__ wq,
    const bf16_t* __restrict__ wk, const bf16_t* __restrict__ wv,
    bf16_t* __restrict__ qo, bf16_t* __restrict__ ko, bf16_t* __restrict__ vt) {
  __shared__ bf16_t lA[128 * 64];
  __shared__ bf16_t lB[128 * 64];
  const int z = blockIdx.z;
  const bf16_t* W = (z == 0) ? wq : ((z == 1) ? wk : wv);
  bf16_t* outb = (z == 0) ? qo : ((z == 1) ? ko : vt);
  const int row0 = blockIdx.y * 128, col0 = blockIdx.x * 128;
  f32x4 acc[4][4] = {};
  gemm_mainloop(xb, W, lA, lB, row0, col0, acc);
  const int lane = threadIdx.x & 63, wave = threadIdx.x >> 6;
  const int wr = wave >> 1, wc = wave & 1;
#pragma unroll
  for (int m = 0; m < 4; ++m) {
#pragma unroll
    for (int n = 0; n < 4; ++n) {
      const int gr = row0 + wr * 64 + m * 16 + ((lane >> 4) << 2);
      const int gc = col0 + wc * 64 + n * 16 + (lane & 15);
      const int b = gr >> 11, t = gr & (T_ - 1);
      const int h = gc >> 6, d = gc & 63;
      if (z < 2) {
#pragma unroll
        for (int j = 0; j < 4; ++j)
          outb[(((size_t)(b * H_ + h)) * T_ + (t + j)) * D_ + d] =
              (bf16_t)acc[m][n][j];
      } else {
        bf16x4 pk = {(bf16_t)acc[m][n][0], (bf16_t)acc[m][n][1],
                     (bf16_t)acc[m][n][2], (bf16_t)acc[m][n][3]};
        *(bf16x4*)(outb + (((size_t)(b * H_ + h)) * D_ + d) * T_ + t) = pk;
      }
    }
  }
}

// Output projection + bias, f32 out.
__global__ __launch_bounds__(256) void gemm_proj(const bf16_t* __restrict__ att,
                                                 const bf16_t* __restrict__ wp,
                                                 const float* __restrict__ bias,
                                                 float* __restrict__ out) {
  __shared__ bf16_t lA[128 * 64];
  __shared__ bf16_t lB[128 * 64];
  const int row0 = blockIdx.y * 128, col0 = blockIdx.x * 128;
  f32x4 acc[4][4] = {};
  gemm_mainloop(att, wp, lA, lB, row0, col0, acc);
  const int lane = threadIdx.x & 63, wave = threadIdx.x >> 6;
  const int wr = wave >> 1, wc = wave & 1;
#pragma unroll
  for (int m = 0; m < 4; ++m) {
#pragma unroll
    for (int n = 0; n < 4; ++n) {
      const int gr = row0 + wr * 64 + m * 16 + ((lane >> 4) << 2);
      const int gc = col0 + wc * 64 + n * 16 + (lane & 15);
      const float bv = bias[gc];
#pragma unroll
      for (int j = 0; j < 4; ++j)
        out[(size_t)(gr + j) * C_ + gc] = acc[m][n][j] + bv;
    }
  }
}

// --------------------------------------------------------- flash attention
// grid: x = q-tile (64 rows, 4 waves x 16), y = b*h. Causal: iterate KV tiles
// 0..blockIdx.x; only the diagonal tile needs masking.
__global__ __launch_bounds__(256) void attn_fwd(const bf16_t* __restrict__ Q,
                                                const bf16_t* __restrict__ K,
                                                const bf16_t* __restrict__ V,
                                                bf16_t* __restrict__ AO) {
  __shared__ bf16_t lK[64 * 64];
  __shared__ bf16_t lV[64 * 64];       // V^T tile: [d][s]
  __shared__ bf16_t lP[4][16 * 64];    // per-wave P re-layout buffer
  const int tid = threadIdx.x, wave = tid >> 6, lane = tid & 63;
  const int bh = blockIdx.y;
  const int t0 = blockIdx.x * 64;
  const int tw = t0 + wave * 16;
  const size_t baseK = (size_t)bh * T_ * D_;
  const size_t baseV = (size_t)bh * D_ * T_;
  bf16x8 qf[2];
#pragma unroll
  for (int s = 0; s < 2; ++s)
    qf[s] = *(const bf16x8*)(Q + baseK + (size_t)(tw + (lane & 15)) * D_ +
                             s * 32 + ((lane >> 4) << 3));
  float mrun[4], lrun[4];
  f32x4 o[4] = {};
#pragma unroll
  for (int j = 0; j < 4; ++j) {
    mrun[j] = -1e30f;
    lrun[j] = 0.f;
  }
  const int ntiles = blockIdx.x + 1;
  for (int it = 0; it < ntiles; ++it) {
    const int s0 = it * 64;
#pragma unroll
    for (int half = 0; half < 2; ++half) {
      const int off = (wave * 2 + half) * 1024;
      const int lin = off + lane * 16;
      const int r = lin >> 7;
      const int c = ((lin >> 4) & 7) ^ (r & 7);
      GLDS(K + baseK + (size_t)(s0 + r) * D_ + c * 8, lK + (off >> 1));
      GLDS(V + baseV + (size_t)r * T_ + s0 + c * 8, lV + (off >> 1));
    }
    __syncthreads();
    // S = Q K^T * 1/8, per wave 16 x 64
    f32x4 sc[4];
#pragma unroll
    for (int nf = 0; nf < 4; ++nf) {
      f32x4 a = {};
#pragma unroll
      for (int s = 0; s < 2; ++s) {
        const int r = nf * 16 + (lane & 15);
        const int c = s * 4 + (lane >> 4);
        bf16x8 kf = *(const bf16x8*)((const char*)lK + r * 128 +
                                     ((c ^ (r & 7)) << 4));
        a = mfma16(qf[s], kf, a);
      }
#pragma unroll
      for (int j = 0; j < 4; ++j) sc[nf][j] = a[j] * 0.125f;
    }
    if (it == blockIdx.x) {  // diagonal tile: causal mask
#pragma unroll
      for (int nf = 0; nf < 4; ++nf)
#pragma unroll
        for (int j = 0; j < 4; ++j) {
          const int s = s0 + nf * 16 + (lane & 15);
          const int t = tw + ((lane >> 4) << 2) + j;
          if (s > t) sc[nf][j] = -1e30f;
        }
    }
    // online softmax (row stats live in all 16 lanes of the group)
#pragma unroll
    for (int j = 0; j < 4; ++j) {
      float v = fmaxf(fmaxf(sc[0][j], sc[1][j]), fmaxf(sc[2][j], sc[3][j]));
#pragma unroll
      for (int d = 1; d < 16; d <<= 1) v = fmaxf(v, __shfl_xor(v, d));
      const float mn = fmaxf(mrun[j], v);
      const float scl = __expf(mrun[j] - mn);
      mrun[j] = mn;
      float ps = 0.f;
#pragma unroll
      for (int nf = 0; nf < 4; ++nf) {
        const float p = __expf(sc[nf][j] - mn);
        sc[nf][j] = p;
        ps += p;
      }
#pragma unroll
      for (int d = 1; d < 16; d <<= 1) ps += __shfl_xor(ps, d);
      lrun[j] = lrun[j] * scl + ps;
#pragma unroll
      for (int df = 0; df < 4; ++df) o[df][j] *= scl;
    }
    // P (C-layout) -> LDS (swizzled) to re-read as MFMA A-frags
#pragma unroll
    for (int nf = 0; nf < 4; ++nf)
#pragma unroll
      for (int j = 0; j < 4; ++j) {
        const int r = ((lane >> 4) << 2) + j;
        const int s = nf * 16 + (lane & 15);
        *(bf16_t*)((char*)lP[wave] + r * 128 + (((s >> 3) ^ (r & 7)) << 4) +
                   ((s & 7) << 1)) = (bf16_t)sc[nf][j];
      }
    // O += P V  (B-operand = V^T rows, natural N x K)
#pragma unroll
    for (int s2 = 0; s2 < 2; ++s2) {
      const int rp = lane & 15;
      const int cp = s2 * 4 + (lane >> 4);
      bf16x8 pf = *(const bf16x8*)((const char*)lP[wave] + rp * 128 +
                                   ((cp ^ (rp & 7)) << 4));
#pragma unroll
      for (int df = 0; df < 4; ++df) {
        const int rv = df * 16 + (lane & 15);
        bf16x8 vf = *(const bf16x8*)((const char*)lV + rv * 128 +
                                     ((cp ^ (rv & 7)) << 4));
        o[df] = mfma16(pf, vf, o[df]);
      }
    }
    __syncthreads();
  }
  const int bb = bh >> 4, hh = bh & 15;
#pragma unroll
  for (int j = 0; j < 4; ++j) {
    const float inv = 1.0f / lrun[j];
    const int t = tw + ((lane >> 4) << 2) + j;
#pragma unroll
    for (int df = 0; df < 4; ++df) {
      const int cc = hh * 64 + df * 16 + (lane & 15);
      AO[((size_t)(bb * T_ + t)) * C_ + cc] = (bf16_t)(o[df][j] * inv);
    }
  }
}

// ---------------------------------------------------------------- launcher
extern "C" void kernel_launch(void* const* d_in, const int* in_sizes, int n_in,
                              void* d_out, int out_size, void* d_ws,
                              size_t ws_size, hipStream_t stream) {
  const float* x = (const float*)d_in[0];
  const float* Wk = (const float*)d_in[1];
  const float* Wq = (const float*)d_in[2];
  const float* Wv = (const float*)d_in[3];
  const float* Wp = (const float*)d_in[4];
  const float* bp = (const float*)d_in[5];
  char* ws = (char*)d_ws;
  // workspace layout (72 MiB):
  bf16_t* xb = (bf16_t*)ws;                          // 16 MiB (reused as att)
  bf16_t* wqb = (bf16_t*)(ws + (16u << 20));         // 2 MiB
  bf16_t* wkb = (bf16_t*)(ws + (18u << 20));         // 2 MiB
  bf16_t* wvb = (bf16_t*)(ws + (20u << 20));         // 2 MiB
  bf16_t* wpb = (bf16_t*)(ws + (22u << 20));         // 2 MiB
  bf16_t* q = (bf16_t*)(ws + (24u << 20));           // 16 MiB [B][H][T][D]
  bf16_t* k = (bf16_t*)(ws + (40u << 20));           // 16 MiB [B][H][T][D]
  bf16_t* vt = (bf16_t*)(ws + (56u << 20));          // 16 MiB [B][H][D][T]
  bf16_t* att = xb;  // x no longer needed once QKV GEMMs are done

  cvt_f32_bf16<<<8192, 256, 0, stream>>>(x, xb, 2097152);
  cvt_f32_bf16<<<1024, 256, 0, stream>>>(Wq, wqb, 262144);
  cvt_f32_bf16<<<1024, 256, 0, stream>>>(Wk, wkb, 262144);
  cvt_f32_bf16<<<1024, 256, 0, stream>>>(Wv, wvb, 262144);
  cvt_f32_bf16<<<1024, 256, 0, stream>>>(Wp, wpb, 262144);
  gemm_qkv<<<dim3(8, 64, 3), 256, 0, stream>>>(xb, wqb, wkb, wvb, q, k, vt);
  attn_fwd<<<dim3(32, 64), 256, 0, stream>>>(q, k, vt, att);
  gemm_proj<<<dim3(8, 64), 256, 0, stream>>>(att, wpb, bp, (float*)d_out);
}

// Round 2
// 253.226 us; speedup vs baseline: 1.4399x; 1.4399x over previous
//
#include <hip/hip_runtime.h>

typedef __bf16 bf16_t;
typedef bf16_t bf16x4 __attribute__((ext_vector_type(4)));
typedef bf16_t bf16x8 __attribute__((ext_vector_type(8)));
typedef float f32x4 __attribute__((ext_vector_type(4)));

#define B_ 4
#define T_ 2048
#define C_ 1024
#define H_ 16
#define D_ 64

// global -> LDS direct copy, 16B per lane; LDS dest must be wave-uniform base
// (HW adds lane*16). Source is per-lane (pre-swizzled to realize LDS swizzle).
#define GLDS(g, l)                                                          \
  __builtin_amdgcn_global_load_lds(                                         \
      (const __attribute__((address_space(1))) void*)(g),                   \
      (__attribute__((address_space(3))) void*)(l), 16, 0, 0)

static __device__ __forceinline__ f32x4 mfma16(bf16x8 a, bf16x8 b, f32x4 c) {
  return __builtin_amdgcn_mfma_f32_16x16x32_bf16(a, b, c, 0, 0, 0);
}

// ---------------------------------------------------------------- convert
__global__ void cvt_f32_bf16(const float* __restrict__ in,
                             bf16_t* __restrict__ out, int n4) {
  int i = blockIdx.x * blockDim.x + threadIdx.x;
  if (i < n4) {
    float4 v = ((const float4*)in)[i];
    bf16x4 o = {(bf16_t)v.x, (bf16_t)v.y, (bf16_t)v.z, (bf16_t)v.w};
    ((bf16x4*)out)[i] = o;
  }
}

// ------------------------------------------------------------ GEMM main loop
// C = A(MxK) * W(NxK)^T, 128x128 tile, BK=64, 256 threads = 2x2 waves,
// each wave 64x64 = 4x4 fragments of 16x16x32 bf16 MFMA.
// LDS tiles [128 rows][64 bf16] (128B rows), XOR-swizzled 16B chunks:
// phys_chunk = chunk ^ (row & 7). Staged linearly via global_load_lds with
// inverse-swizzled global source (same involution).
__device__ __forceinline__ void gemm_mainloop(const bf16_t* __restrict__ A,
                                              const bf16_t* __restrict__ W,
                                              bf16_t* lA, bf16_t* lB, int row0,
                                              int col0, f32x4 (&acc)[4][4]) {
  const int tid = threadIdx.x;
  const int wave = tid >> 6, lane = tid & 63;
  const int wr = wave >> 1, wc = wave & 1;
  for (int k0 = 0; k0 < C_; k0 += 64) {
#pragma unroll
    for (int it = 0; it < 4; ++it) {
      const int off = (it * 4 + wave) * 1024;  // bytes, wave-uniform
      const int lin = off + lane * 16;
      const int r = lin >> 7;
      const int c = ((lin >> 4) & 7) ^ (r & 7);
      GLDS(A + (size_t)(row0 + r) * C_ + k0 + c * 8, lA + (off >> 1));
      GLDS(W + (size_t)(col0 + r) * C_ + k0 + c * 8, lB + (off >> 1));
    }
    __syncthreads();
#pragma unroll
    for (int s = 0; s < 2; ++s) {
      bf16x8 af[4], bfr[4];
#pragma unroll
      for (int m = 0; m < 4; ++m) {
        const int r = wr * 64 + m * 16 + (lane & 15);
        const int c = s * 4 + (lane >> 4);
        af[m] = *(const bf16x8*)((const char*)lA + r * 128 +
                                 ((c ^ (r & 7)) << 4));
      }
#pragma unroll
      for (int n = 0; n < 4; ++n) {
        const int r = wc * 64 + n * 16 + (lane & 15);
        const int c = s * 4 + (lane >> 4);
        bfr[n] = *(const bf16x8*)((const char*)lB + r * 128 +
                                  ((c ^ (r & 7)) << 4));
      }
#pragma unroll
      for (int m = 0; m < 4; ++m)
#pragma unroll
        for (int n = 0; n < 4; ++n) acc[m][n] = mfma16(af[m], bfr[n], acc[m][n]);
    }
    __syncthreads();
  }
}

// QKV projection. z=0: Q -> [B][H][T][D]; z=1: K -> [B][H][T][D];
// z=2: V -> transposed [B][H][D][T] so PV's B-operand is natural N x K.
__global__ __launch_bounds__(256) void gemm_qkv(
    const bf16_t* __restrict__ xb, const bf16_t* __restrict__ wq,
    const bf16_t* __restrict__ wk, const bf16_t* __restrict__ wv,
    bf16_t* __restrict__ qo, bf16_t* __restrict__ ko, bf16_t* __restrict__ vt) {
  __shared__ bf16_t lA[128 * 64];
  __shared__ bf16_t lB[128 * 64];
  const int z = blockIdx.z;
  const bf16_t* W = (z == 0) ? wq : ((z == 1) ? wk : wv);
  bf16_t* outb = (z == 0) ? qo : ((z == 1) ? ko : vt);
  const int row0 = blockIdx.y * 128, col0 = blockIdx.x * 128;
  f32x4 acc[4][4] = {};
  gemm_mainloop(xb, W, lA, lB, row0, col0, acc);
  const int lane = threadIdx.x & 63, wave = threadIdx.x >> 6;
  const int wr = wave >> 1, wc = wave & 1;
#pragma unroll
  for (int m = 0; m < 4; ++m) {
#pragma unroll
    for (int n = 0; n < 4; ++n) {
      const int gr = row0 + wr * 64 + m * 16 + ((lane >> 4) << 2);
      const int gc = col0 + wc * 64 + n * 16 + (lane & 15);
      const int b = gr >> 11, t = gr & (T_ - 1);
      const int h = gc >> 6, d = gc & 63;
      if (z < 2) {
#pragma unroll
        for (int j = 0; j < 4; ++j)
          outb[(((size_t)(b * H_ + h)) * T_ + (t + j)) * D_ + d] =
              (bf16_t)acc[m][n][j];
      } else {
        bf16x4 pk = {(bf16_t)acc[m][n][0], (bf16_t)acc[m][n][1],
                     (bf16_t)acc[m][n][2], (bf16_t)acc[m][n][3]};
        *(bf16x4*)(outb + (((size_t)(b * H_ + h)) * D_ + d) * T_ + t) = pk;
      }
    }
  }
}

// Output projection + bias, f32 out.
__global__ __launch_bounds__(256) void gemm_proj(const bf16_t* __restrict__ att,
                                                 const bf16_t* __restrict__ wp,
                                                 const float* __restrict__ bias,
                                                 float* __restrict__ out) {
  __shared__ bf16_t lA[128 * 64];
  __shared__ bf16_t lB[128 * 64];
  const int row0 = blockIdx.y * 128, col0 = blockIdx.x * 128;
  f32x4 acc[4][4] = {};
  gemm_mainloop(att, wp, lA, lB, row0, col0, acc);
  const int lane = threadIdx.x & 63, wave = threadIdx.x >> 6;
  const int wr = wave >> 1, wc = wave & 1;
#pragma unroll
  for (int m = 0; m < 4; ++m) {
#pragma unroll
    for (int n = 0; n < 4; ++n) {
      const int gr = row0 + wr * 64 + m * 16 + ((lane >> 4) << 2);
      const int gc = col0 + wc * 64 + n * 16 + (lane & 15);
      const float bv = bias[gc];
#pragma unroll
      for (int j = 0; j < 4; ++j)
        out[(size_t)(gr + j) * C_ + gc] = acc[m][n][j] + bv;
    }
  }
}

// --------------------------------------------------------- flash attention v2
// Work-balanced + double-buffered.
// grid: x = pair id (8), y = b*h (64). Each block handles q-tiles
// qt = x and 15-x (128 rows each) sequentially -> exactly 34 KV iterations
// per block. 4 waves, each wave owns 32 q-rows (2 m-frags).
// K/V tiles (KVBLK=64) double-buffered in LDS; stage(it+1) issued before
// compute(it), single barrier per iteration at loop top (the implicit
// vmcnt(0)+lgkmcnt(0) drain before s_barrier completes the staging).
__global__ __launch_bounds__(256) void attn_fwd(const bf16_t* __restrict__ Q,
                                                const bf16_t* __restrict__ K,
                                                const bf16_t* __restrict__ V,
                                                bf16_t* __restrict__ AO) {
  __shared__ bf16_t lK[2][64 * 64];
  __shared__ bf16_t lV[2][64 * 64];   // V^T tile: [d][s]
  __shared__ bf16_t lP[4][32 * 64];   // per-wave P re-layout buffer
  const int tid = threadIdx.x, wave = tid >> 6, lane = tid & 63;
  const int bh = blockIdx.y;
  const size_t baseK = (size_t)bh * T_ * D_;
  const size_t baseV = (size_t)bh * D_ * T_;
  const int bb = bh >> 4, hh = bh & 15;

  for (int half = 0; half < 2; ++half) {
    const int qt = half ? (15 - blockIdx.x) : blockIdx.x;
    const int tw = qt * 128 + wave * 32;
    const int ntiles = 2 * qt + 2;
    __syncthreads();  // protect LDS buffers from previous half's readers
    // prologue: stage tile 0 into buf 0
    {
      const int s0 = 0;
#pragma unroll
      for (int i = 0; i < 2; ++i) {
        const int off = (i * 4 + wave) * 1024;
        const int lin = off + lane * 16;
        const int r = lin >> 7;
        const int c = ((lin >> 4) & 7) ^ (r & 7);
        GLDS(K + baseK + (size_t)(s0 + r) * D_ + c * 8, &lK[0][off >> 1]);
        GLDS(V + baseV + (size_t)r * T_ + s0 + c * 8, &lV[0][off >> 1]);
      }
    }
    // Q fragments (A-operand), rows tw+16m+(lane&15), k = s*32+(lane>>4)*8
    bf16x8 qf[2][2];
#pragma unroll
    for (int m = 0; m < 2; ++m)
#pragma unroll
      for (int s = 0; s < 2; ++s)
        qf[m][s] = *(const bf16x8*)(Q + baseK +
                                    (size_t)(tw + 16 * m + (lane & 15)) * D_ +
                                    s * 32 + ((lane >> 4) << 3));
    float mrun[2][4], lrun[2][4];
    f32x4 o[2][4] = {};
#pragma unroll
    for (int m = 0; m < 2; ++m)
#pragma unroll
      for (int j = 0; j < 4; ++j) {
        mrun[m][j] = -1e30f;
        lrun[m][j] = 0.f;
      }
    int cur = 0;
    for (int it = 0; it < ntiles; ++it) {
      __syncthreads();  // staging into `cur` complete; readers of cur^1 done
      if (it + 1 < ntiles) {
        const int s0n = (it + 1) * 64;
        const int nb = cur ^ 1;
#pragma unroll
        for (int i = 0; i < 2; ++i) {
          const int off = (i * 4 + wave) * 1024;
          const int lin = off + lane * 16;
          const int r = lin >> 7;
          const int c = ((lin >> 4) & 7) ^ (r & 7);
          GLDS(K + baseK + (size_t)(s0n + r) * D_ + c * 8, &lK[nb][off >> 1]);
          GLDS(V + baseV + (size_t)r * T_ + s0n + c * 8, &lV[nb][off >> 1]);
        }
      }
      const int s0 = it * 64;
      // S = Q K^T, per wave 32 x 64
      f32x4 sc[2][4];
#pragma unroll
      for (int m = 0; m < 2; ++m)
#pragma unroll
        for (int nf = 0; nf < 4; ++nf) sc[m][nf] = (f32x4){};
#pragma unroll
      for (int s = 0; s < 2; ++s) {
#pragma unroll
        for (int nf = 0; nf < 4; ++nf) {
          const int r = nf * 16 + (lane & 15);
          const int c = s * 4 + (lane >> 4);
          bf16x8 kf = *(const bf16x8*)((const char*)lK[cur] + r * 128 +
                                       ((c ^ (r & 7)) << 4));
#pragma unroll
          for (int m = 0; m < 2; ++m) sc[m][nf] = mfma16(qf[m][s], kf, sc[m][nf]);
        }
      }
      // scale + causal mask (only the last two tiles of this q-tile touch
      // the diagonal)
      const bool diag = (it >= 2 * qt);
#pragma unroll
      for (int m = 0; m < 2; ++m)
#pragma unroll
        for (int nf = 0; nf < 4; ++nf)
#pragma unroll
          for (int j = 0; j < 4; ++j) {
            float val = sc[m][nf][j] * 0.125f;
            if (diag) {
              const int s = s0 + nf * 16 + (lane & 15);
              const int t = tw + 16 * m + ((lane >> 4) << 2) + j;
              if (s > t) val = -1e30f;
            }
            sc[m][nf][j] = val;
          }
      // online softmax: row stats live in the 16 lanes sharing (lane>>4)
#pragma unroll
      for (int m = 0; m < 2; ++m)
#pragma unroll
        for (int j = 0; j < 4; ++j) {
          float v = fmaxf(fmaxf(sc[m][0][j], sc[m][1][j]),
                          fmaxf(sc[m][2][j], sc[m][3][j]));
#pragma unroll
          for (int d = 1; d < 16; d <<= 1) v = fmaxf(v, __shfl_xor(v, d));
          const float mn = fmaxf(mrun[m][j], v);
          const float scl = __expf(mrun[m][j] - mn);
          mrun[m][j] = mn;
          float ps = 0.f;
#pragma unroll
          for (int nf = 0; nf < 4; ++nf) {
            const float p = __expf(sc[m][nf][j] - mn);
            sc[m][nf][j] = p;
            ps += p;
          }
#pragma unroll
          for (int d = 1; d < 16; d <<= 1) ps += __shfl_xor(ps, d);
          lrun[m][j] = lrun[m][j] * scl + ps;
#pragma unroll
          for (int df = 0; df < 4; ++df) o[m][df][j] *= scl;
        }
      // P (C-layout) -> LDS (swizzled) to re-read as MFMA A-frags
#pragma unroll
      for (int m = 0; m < 2; ++m)
#pragma unroll
        for (int nf = 0; nf < 4; ++nf)
#pragma unroll
          for (int j = 0; j < 4; ++j) {
            const int r = 16 * m + ((lane >> 4) << 2) + j;
            const int s = nf * 16 + (lane & 15);
            *(bf16_t*)((char*)lP[wave] + r * 128 +
                       (((s >> 3) ^ (r & 7)) << 4) + ((s & 7) << 1)) =
                (bf16_t)sc[m][nf][j];
          }
      // O += P V  (B-operand = V^T rows, natural N x K)
#pragma unroll
      for (int s2 = 0; s2 < 2; ++s2) {
#pragma unroll
        for (int m = 0; m < 2; ++m) {
          const int rp = 16 * m + (lane & 15);
          const int cp = s2 * 4 + (lane >> 4);
          bf16x8 pf = *(const bf16x8*)((const char*)lP[wave] + rp * 128 +
                                       ((cp ^ (rp & 7)) << 4));
#pragma unroll
          for (int df = 0; df < 4; ++df) {
            const int rv = df * 16 + (lane & 15);
            bf16x8 vf = *(const bf16x8*)((const char*)lV[cur] + rv * 128 +
                                         ((cp ^ (rv & 7)) << 4));
            o[m][df] = mfma16(pf, vf, o[m][df]);
          }
        }
      }
      cur ^= 1;
    }
    // epilogue: normalized O -> [B][T][C] bf16
#pragma unroll
    for (int m = 0; m < 2; ++m)
#pragma unroll
      for (int j = 0; j < 4; ++j) {
        const float inv = 1.0f / lrun[m][j];
        const int t = tw + 16 * m + ((lane >> 4) << 2) + j;
#pragma unroll
        for (int df = 0; df < 4; ++df) {
          const int cc = hh * 64 + df * 16 + (lane & 15);
          AO[((size_t)(bb * T_ + t)) * C_ + cc] = (bf16_t)(o[m][df][j] * inv);
        }
      }
  }
}

// ---------------------------------------------------------------- launcher
extern "C" void kernel_launch(void* const* d_in, const int* in_sizes, int n_in,
                              void* d_out, int out_size, void* d_ws,
                              size_t ws_size, hipStream_t stream) {
  const float* x = (const float*)d_in[0];
  const float* Wk = (const float*)d_in[1];
  const float* Wq = (const float*)d_in[2];
  const float* Wv = (const float*)d_in[3];
  const float* Wp = (const float*)d_in[4];
  const float* bp = (const float*)d_in[5];
  char* ws = (char*)d_ws;
  // workspace layout (72 MiB):
  bf16_t* xb = (bf16_t*)ws;                          // 16 MiB (reused as att)
  bf16_t* wqb = (bf16_t*)(ws + (16u << 20));         // 2 MiB
  bf16_t* wkb = (bf16_t*)(ws + (18u << 20));         // 2 MiB
  bf16_t* wvb = (bf16_t*)(ws + (20u << 20));         // 2 MiB
  bf16_t* wpb = (bf16_t*)(ws + (22u << 20));         // 2 MiB
  bf16_t* q = (bf16_t*)(ws + (24u << 20));           // 16 MiB [B][H][T][D]
  bf16_t* k = (bf16_t*)(ws + (40u << 20));           // 16 MiB [B][H][T][D]
  bf16_t* vt = (bf16_t*)(ws + (56u << 20));          // 16 MiB [B][H][D][T]
  bf16_t* att = xb;  // x no longer needed once QKV GEMMs are done

  cvt_f32_bf16<<<8192, 256, 0, stream>>>(x, xb, 2097152);
  cvt_f32_bf16<<<1024, 256, 0, stream>>>(Wq, wqb, 262144);
  cvt_f32_bf16<<<1024, 256, 0, stream>>>(Wk, wkb, 262144);
  cvt_f32_bf16<<<1024, 256, 0, stream>>>(Wv, wvb, 262144);
  cvt_f32_bf16<<<1024, 256, 0, stream>>>(Wp, wpb, 262144);
  gemm_qkv<<<dim3(8, 64, 3), 256, 0, stream>>>(xb, wqb, wkb, wvb, q, k, vt);
  attn_fwd<<<dim3(8, 64), 256, 0, stream>>>(q, k, vt, att);
  gemm_proj<<<dim3(8, 64), 256, 0, stream>>>(att, wpb, bp, (float*)d_out);
}

// Round 3
// 208.641 us; speedup vs baseline: 1.7477x; 1.2137x over previous
//
#include <hip/hip_runtime.h>

typedef __bf16 bf16_t;
typedef bf16_t bf16x4 __attribute__((ext_vector_type(4)));
typedef bf16_t bf16x8 __attribute__((ext_vector_type(8)));
typedef float f32x4 __attribute__((ext_vector_type(4)));

#define B_ 4
#define T_ 2048
#define C_ 1024
#define H_ 16
#define D_ 64

// global -> LDS direct copy, 16B per lane; LDS dest must be wave-uniform base
// (HW adds lane*16). Source is per-lane (pre-swizzled to realize LDS swizzle).
#define GLDS(g, l)                                                          \
  __builtin_amdgcn_global_load_lds(                                         \
      (const __attribute__((address_space(1))) void*)(g),                   \
      (__attribute__((address_space(3))) void*)(l), 16, 0, 0)

static __device__ __forceinline__ f32x4 mfma16(bf16x8 a, bf16x8 b, f32x4 c) {
  return __builtin_amdgcn_mfma_f32_16x16x32_bf16(a, b, c, 0, 0, 0);
}

// ---------------------------------------------------------------- convert
__global__ void cvt_f32_bf16(const float* __restrict__ in,
                             bf16_t* __restrict__ out, int n4) {
  int i = blockIdx.x * blockDim.x + threadIdx.x;
  if (i < n4) {
    float4 v = ((const float4*)in)[i];
    bf16x4 o = {(bf16_t)v.x, (bf16_t)v.y, (bf16_t)v.z, (bf16_t)v.w};
    ((bf16x4*)out)[i] = o;
  }
}

// ------------------------------------------------------------ GEMM main loop
// C = A(MxK) * W(NxK)^T, 128x128 tile, BK=64, 256 threads = 2x2 waves,
// each wave 64x64 = 4x4 fragments of 16x16x32 bf16 MFMA.
// LDS tiles [128 rows][64 bf16] (128B rows), XOR-swizzled 16B chunks:
// phys_chunk = chunk ^ (row & 7). Staged linearly via global_load_lds with
// inverse-swizzled global source (same involution).
__device__ __forceinline__ void gemm_mainloop(const bf16_t* __restrict__ A,
                                              const bf16_t* __restrict__ W,
                                              bf16_t* lA, bf16_t* lB, int row0,
                                              int col0, f32x4 (&acc)[4][4]) {
  const int tid = threadIdx.x;
  const int wave = tid >> 6, lane = tid & 63;
  const int wr = wave >> 1, wc = wave & 1;
  for (int k0 = 0; k0 < C_; k0 += 64) {
#pragma unroll
    for (int it = 0; it < 4; ++it) {
      const int off = (it * 4 + wave) * 1024;  // bytes, wave-uniform
      const int lin = off + lane * 16;
      const int r = lin >> 7;
      const int c = ((lin >> 4) & 7) ^ (r & 7);
      GLDS(A + (size_t)(row0 + r) * C_ + k0 + c * 8, lA + (off >> 1));
      GLDS(W + (size_t)(col0 + r) * C_ + k0 + c * 8, lB + (off >> 1));
    }
    __syncthreads();
#pragma unroll
    for (int s = 0; s < 2; ++s) {
      bf16x8 af[4], bfr[4];
#pragma unroll
      for (int m = 0; m < 4; ++m) {
        const int r = wr * 64 + m * 16 + (lane & 15);
        const int c = s * 4 + (lane >> 4);
        af[m] = *(const bf16x8*)((const char*)lA + r * 128 +
                                 ((c ^ (r & 7)) << 4));
      }
#pragma unroll
      for (int n = 0; n < 4; ++n) {
        const int r = wc * 64 + n * 16 + (lane & 15);
        const int c = s * 4 + (lane >> 4);
        bfr[n] = *(const bf16x8*)((const char*)lB + r * 128 +
                                  ((c ^ (r & 7)) << 4));
      }
#pragma unroll
      for (int m = 0; m < 4; ++m)
#pragma unroll
        for (int n = 0; n < 4; ++n) acc[m][n] = mfma16(af[m], bfr[n], acc[m][n]);
    }
    __syncthreads();
  }
}

// QKV projection. z=0: Q (pre-scaled by 1/sqrt(D)) -> [B][H][T][D];
// z=1: K -> [B][H][T][D]; z=2: V -> transposed [B][H][D][T].
__global__ __launch_bounds__(256) void gemm_qkv(
    const bf16_t* __restrict__ xb, const bf16_t* __restrict__ wq,
    const bf16_t* __restrict__ wk, const bf16_t* __restrict__ wv,
    bf16_t* __restrict__ qo, bf16_t* __restrict__ ko, bf16_t* __restrict__ vt) {
  __shared__ bf16_t lA[128 * 64];
  __shared__ bf16_t lB[128 * 64];
  const int z = blockIdx.z;
  const bf16_t* W = (z == 0) ? wq : ((z == 1) ? wk : wv);
  bf16_t* outb = (z == 0) ? qo : ((z == 1) ? ko : vt);
  const int row0 = blockIdx.y * 128, col0 = blockIdx.x * 128;
  f32x4 acc[4][4] = {};
  gemm_mainloop(xb, W, lA, lB, row0, col0, acc);
  const int lane = threadIdx.x & 63, wave = threadIdx.x >> 6;
  const int wr = wave >> 1, wc = wave & 1;
  const float qs = (z == 0) ? 0.125f : 1.0f;  // fold 1/sqrt(64) into Q
#pragma unroll
  for (int m = 0; m < 4; ++m) {
#pragma unroll
    for (int n = 0; n < 4; ++n) {
      const int gr = row0 + wr * 64 + m * 16 + ((lane >> 4) << 2);
      const int gc = col0 + wc * 64 + n * 16 + (lane & 15);
      const int b = gr >> 11, t = gr & (T_ - 1);
      const int h = gc >> 6, d = gc & 63;
      if (z < 2) {
#pragma unroll
        for (int j = 0; j < 4; ++j)
          outb[(((size_t)(b * H_ + h)) * T_ + (t + j)) * D_ + d] =
              (bf16_t)(acc[m][n][j] * qs);
      } else {
        bf16x4 pk = {(bf16_t)acc[m][n][0], (bf16_t)acc[m][n][1],
                     (bf16_t)acc[m][n][2], (bf16_t)acc[m][n][3]};
        *(bf16x4*)(outb + (((size_t)(b * H_ + h)) * D_ + d) * T_ + t) = pk;
      }
    }
  }
}

// Output projection + bias, f32 out.
__global__ __launch_bounds__(256) void gemm_proj(const bf16_t* __restrict__ att,
                                                 const bf16_t* __restrict__ wp,
                                                 const float* __restrict__ bias,
                                                 float* __restrict__ out) {
  __shared__ bf16_t lA[128 * 64];
  __shared__ bf16_t lB[128 * 64];
  const int row0 = blockIdx.y * 128, col0 = blockIdx.x * 128;
  f32x4 acc[4][4] = {};
  gemm_mainloop(att, wp, lA, lB, row0, col0, acc);
  const int lane = threadIdx.x & 63, wave = threadIdx.x >> 6;
  const int wr = wave >> 1, wc = wave & 1;
#pragma unroll
  for (int m = 0; m < 4; ++m) {
#pragma unroll
    for (int n = 0; n < 4; ++n) {
      const int gr = row0 + wr * 64 + m * 16 + ((lane >> 4) << 2);
      const int gc = col0 + wc * 64 + n * 16 + (lane & 15);
      const float bv = bias[gc];
#pragma unroll
      for (int j = 0; j < 4; ++j)
        out[(size_t)(gr + j) * C_ + gc] = acc[m][n][j] + bv;
    }
  }
}

// --------------------------------------------------------- flash attention v3
// Swapped QK^T: sc = mfma(K, Q) -> S^T, so each lane holds 16 scores of ONE
// q-row (q = lane&15, kv = nf*16 + (lane>>4)*4 + j). Softmax is 15 local
// fmax/adds + 2 shfl_xor hops; scl/inv broadcast back to O-layout lanes via
// 4 single-hop shfls per m-frag. P-repack packs bf16x4 -> 8 ds_write_b64.
// Work-balanced (q-tiles x and 15-x), double-buffered K/V.
__global__ __launch_bounds__(256) void attn_fwd(const bf16_t* __restrict__ Q,
                                                const bf16_t* __restrict__ K,
                                                const bf16_t* __restrict__ V,
                                                bf16_t* __restrict__ AO) {
  __shared__ bf16_t lK[2][64 * 64];
  __shared__ bf16_t lV[2][64 * 64];   // V^T tile: [d][s]
  __shared__ bf16_t lP[4][32 * 64];   // per-wave P re-layout buffer
  const int tid = threadIdx.x, wave = tid >> 6, lane = tid & 63;
  const int g = lane >> 4;            // 16-lane group id
  const int bh = blockIdx.y;
  const size_t baseK = (size_t)bh * T_ * D_;
  const size_t baseV = (size_t)bh * D_ * T_;
  const int bb = bh >> 4, hh = bh & 15;

  for (int half = 0; half < 2; ++half) {
    const int qt = half ? (15 - blockIdx.x) : blockIdx.x;
    const int tw = qt * 128 + wave * 32;
    const int ntiles = 2 * qt + 2;
    __syncthreads();  // protect LDS buffers from previous half's readers
    // prologue: stage tile 0 into buf 0
    {
#pragma unroll
      for (int i = 0; i < 2; ++i) {
        const int off = (i * 4 + wave) * 1024;
        const int lin = off + lane * 16;
        const int r = lin >> 7;
        const int c = ((lin >> 4) & 7) ^ (r & 7);
        GLDS(K + baseK + (size_t)r * D_ + c * 8, &lK[0][off >> 1]);
        GLDS(V + baseV + (size_t)r * T_ + c * 8, &lV[0][off >> 1]);
      }
    }
    // Q fragments (operand layout: row=lane&15, k=(lane>>4)*8+e), Q already
    // pre-scaled by 1/sqrt(D) in the QKV GEMM.
    bf16x8 qf[2][2];
#pragma unroll
    for (int m = 0; m < 2; ++m)
#pragma unroll
      for (int s = 0; s < 2; ++s)
        qf[m][s] = *(const bf16x8*)(Q + baseK +
                                    (size_t)(tw + 16 * m + (lane & 15)) * D_ +
                                    s * 32 + (g << 3));
    float mrun[2], lrun[2];
    f32x4 o[2][4] = {};
#pragma unroll
    for (int m = 0; m < 2; ++m) {
      mrun[m] = -1e30f;
      lrun[m] = 0.f;
    }
    int cur = 0;
    for (int it = 0; it < ntiles; ++it) {
      __syncthreads();  // staging into `cur` complete; readers of cur^1 done
      if (it + 1 < ntiles) {
        const int s0n = (it + 1) * 64;
        const int nb = cur ^ 1;
#pragma unroll
        for (int i = 0; i < 2; ++i) {
          const int off = (i * 4 + wave) * 1024;
          const int lin = off + lane * 16;
          const int r = lin >> 7;
          const int c = ((lin >> 4) & 7) ^ (r & 7);
          GLDS(K + baseK + (size_t)(s0n + r) * D_ + c * 8, &lK[nb][off >> 1]);
          GLDS(V + baseV + (size_t)r * T_ + s0n + c * 8, &lV[nb][off >> 1]);
        }
      }
      const int s0 = it * 64;
      // S^T = K Q^T per wave: rows kv (4 nf-frags), cols q (2 m-frags)
      f32x4 sc[2][4];
#pragma unroll
      for (int m = 0; m < 2; ++m)
#pragma unroll
        for (int nf = 0; nf < 4; ++nf) sc[m][nf] = (f32x4){};
      __builtin_amdgcn_s_setprio(1);
#pragma unroll
      for (int s = 0; s < 2; ++s) {
#pragma unroll
        for (int nf = 0; nf < 4; ++nf) {
          const int r = nf * 16 + (lane & 15);
          const int c = s * 4 + g;
          bf16x8 kf = *(const bf16x8*)((const char*)lK[cur] + r * 128 +
                                       ((c ^ (r & 7)) << 4));
#pragma unroll
          for (int m = 0; m < 2; ++m)
            sc[m][nf] = mfma16(kf, qf[m][s], sc[m][nf]);  // swapped operands
        }
      }
      __builtin_amdgcn_s_setprio(0);
      // causal mask (only the last two tiles of this q-tile touch diagonal)
      const bool dtile = (it >= 2 * qt);
      if (dtile) {
#pragma unroll
        for (int m = 0; m < 2; ++m) {
          const int t = tw + 16 * m + (lane & 15);
#pragma unroll
          for (int nf = 0; nf < 4; ++nf)
#pragma unroll
            for (int j = 0; j < 4; ++j) {
              const int s = s0 + nf * 16 + g * 4 + j;
              if (s > t) sc[m][nf][j] = -1e30f;
            }
        }
      }
      // online softmax: entire q-row is lane-local (16 values) + 2 hops
#pragma unroll
      for (int m = 0; m < 2; ++m) {
        float pmax = sc[m][0][0];
#pragma unroll
        for (int nf = 0; nf < 4; ++nf)
#pragma unroll
          for (int j = 0; j < 4; ++j) pmax = fmaxf(pmax, sc[m][nf][j]);
        pmax = fmaxf(pmax, __shfl_xor(pmax, 16));
        pmax = fmaxf(pmax, __shfl_xor(pmax, 32));
        const float mn = fmaxf(mrun[m], pmax);
        const float scl = __expf(mrun[m] - mn);
        mrun[m] = mn;
        float ps = 0.f;
        bf16x4 pk[4];
#pragma unroll
        for (int nf = 0; nf < 4; ++nf)
#pragma unroll
          for (int j = 0; j < 4; ++j) {
            const float p = __expf(sc[m][nf][j] - mn);
            ps += p;
            pk[nf][j] = (bf16_t)p;
          }
        ps += __shfl_xor(ps, 16);
        ps += __shfl_xor(ps, 32);
        lrun[m] = lrun[m] * scl + ps;
        // broadcast scl from q-col holders to O-row holders, rescale O
        float sb[4];
#pragma unroll
        for (int j = 0; j < 4; ++j)
          sb[j] = __shfl(scl, (lane & 48) | ((g << 2) + j));
#pragma unroll
        for (int df = 0; df < 4; ++df)
#pragma unroll
          for (int j = 0; j < 4; ++j) o[m][df][j] *= sb[j];
        // P -> LDS: row q, packed bf16x4 per nf (same XOR-16B involution)
        const int r = 16 * m + (lane & 15);
#pragma unroll
        for (int nf = 0; nf < 4; ++nf)
          *(bf16x4*)((char*)lP[wave] + r * 128 +
                     ((((2 * nf + (g >> 1)) ^ (r & 7)) << 4) | ((g & 1) << 3))) =
              pk[nf];
      }
      // O += P V  (A = P rows q, B = V^T rows d, K = kv)
      __builtin_amdgcn_s_setprio(1);
#pragma unroll
      for (int s2 = 0; s2 < 2; ++s2) {
#pragma unroll
        for (int m = 0; m < 2; ++m) {
          const int rp = 16 * m + (lane & 15);
          const int cp = s2 * 4 + g;
          bf16x8 pf = *(const bf16x8*)((const char*)lP[wave] + rp * 128 +
                                       ((cp ^ (rp & 7)) << 4));
#pragma unroll
          for (int df = 0; df < 4; ++df) {
            const int rv = df * 16 + (lane & 15);
            bf16x8 vf = *(const bf16x8*)((const char*)lV[cur] + rv * 128 +
                                         ((cp ^ (rv & 7)) << 4));
            o[m][df] = mfma16(pf, vf, o[m][df]);
          }
        }
      }
      __builtin_amdgcn_s_setprio(0);
      cur ^= 1;
    }
    // epilogue: normalized O -> [B][T][C] bf16 (broadcast 1/l to row holders)
#pragma unroll
    for (int m = 0; m < 2; ++m) {
      const float inv = 1.0f / lrun[m];
      float ib[4];
#pragma unroll
      for (int j = 0; j < 4; ++j)
        ib[j] = __shfl(inv, (lane & 48) | ((g << 2) + j));
#pragma unroll
      for (int j = 0; j < 4; ++j) {
        const int t = tw + 16 * m + (g << 2) + j;
#pragma unroll
        for (int df = 0; df < 4; ++df) {
          const int cc = hh * 64 + df * 16 + (lane & 15);
          AO[((size_t)(bb * T_ + t)) * C_ + cc] = (bf16_t)(o[m][df][j] * ib[j]);
        }
      }
    }
  }
}

// ---------------------------------------------------------------- launcher
extern "C" void kernel_launch(void* const* d_in, const int* in_sizes, int n_in,
                              void* d_out, int out_size, void* d_ws,
                              size_t ws_size, hipStream_t stream) {
  const float* x = (const float*)d_in[0];
  const float* Wk = (const float*)d_in[1];
  const float* Wq = (const float*)d_in[2];
  const float* Wv = (const float*)d_in[3];
  const float* Wp = (const float*)d_in[4];
  const float* bp = (const float*)d_in[5];
  char* ws = (char*)d_ws;
  // workspace layout (72 MiB):
  bf16_t* xb = (bf16_t*)ws;                          // 16 MiB (reused as att)
  bf16_t* wqb = (bf16_t*)(ws + (16u << 20));         // 2 MiB
  bf16_t* wkb = (bf16_t*)(ws + (18u << 20));         // 2 MiB
  bf16_t* wvb = (bf16_t*)(ws + (20u << 20));         // 2 MiB
  bf16_t* wpb = (bf16_t*)(ws + (22u << 20));         // 2 MiB
  bf16_t* q = (bf16_t*)(ws + (24u << 20));           // 16 MiB [B][H][T][D]
  bf16_t* k = (bf16_t*)(ws + (40u << 20));           // 16 MiB [B][H][T][D]
  bf16_t* vt = (bf16_t*)(ws + (56u << 20));          // 16 MiB [B][H][D][T]
  bf16_t* att = xb;  // x no longer needed once QKV GEMMs are done

  cvt_f32_bf16<<<8192, 256, 0, stream>>>(x, xb, 2097152);
  cvt_f32_bf16<<<1024, 256, 0, stream>>>(Wq, wqb, 262144);
  cvt_f32_bf16<<<1024, 256, 0, stream>>>(Wk, wkb, 262144);
  cvt_f32_bf16<<<1024, 256, 0, stream>>>(Wv, wvb, 262144);
  cvt_f32_bf16<<<1024, 256, 0, stream>>>(Wp, wpb, 262144);
  gemm_qkv<<<dim3(8, 64, 3), 256, 0, stream>>>(xb, wqb, wkb, wvb, q, k, vt);
  attn_fwd<<<dim3(8, 64), 256, 0, stream>>>(q, k, vt, att);
  gemm_proj<<<dim3(8, 64), 256, 0, stream>>>(att, wpb, bp, (float*)d_out);
}